// Round 4
// baseline (652.058 us; speedup 1.0000x reference)
//
#include <hip/hip_runtime.h>

typedef __bf16 bf16_t;
typedef bf16_t bf16x8 __attribute__((ext_vector_type(8)));
typedef bf16_t bf16x4 __attribute__((ext_vector_type(4)));
typedef float f32x4 __attribute__((ext_vector_type(4)));

#define N_NODES 8192
#define DIM 512

// ---- transpose + convert: x [8192,512] f32 -> xT [512,8192] bf16 ------------
__global__ __launch_bounds__(256) void k_transpose_x(const float* __restrict__ x,
                                                     bf16_t* __restrict__ xT) {
  __shared__ float tile[64][65];
  const int m0 = blockIdx.x * 64;
  const int n0 = blockIdx.y * 64;
  const int t = threadIdx.x;
  const int r = t >> 4;
  const int c = (t & 15) << 2;
#pragma unroll
  for (int i = 0; i < 4; ++i) {
    f32x4 v = *(const f32x4*)&x[(size_t)(m0 + r + i * 16) * DIM + n0 + c];
    tile[r + i * 16][c + 0] = v.x;
    tile[r + i * 16][c + 1] = v.y;
    tile[r + i * 16][c + 2] = v.z;
    tile[r + i * 16][c + 3] = v.w;
  }
  __syncthreads();
#pragma unroll
  for (int i = 0; i < 4; ++i) {
    const int rn = r + i * 16;
    bf16x4 o = {(bf16_t)tile[c + 0][rn], (bf16_t)tile[c + 1][rn],
                (bf16_t)tile[c + 2][rn], (bf16_t)tile[c + 3][rn]};
    *(bf16x4*)&xT[(size_t)(n0 + rn) * N_NODES + m0 + c] = o;
  }
}

// ---- convert W [512,512] f32 -> bf16 ---------------------------------------
__global__ __launch_bounds__(256) void k_cvt_w(const float* __restrict__ W,
                                               bf16_t* __restrict__ Wb) {
  const int t = blockIdx.x * 256 + threadIdx.x;
  f32x4 v = *(const f32x4*)&W[(size_t)t * 4];
  bf16x4 o = {(bf16_t)v.x, (bf16_t)v.y, (bf16_t)v.z, (bf16_t)v.w};
  *(bf16x4*)&Wb[(size_t)t * 4] = o;
}

// ---- GEMM1: P[s] = adj[:, chunk] @ xT[chunk, :]  (fp32 partials) ------------
// 128x128 tile, BK=32, 512 thr = 8 waves in 4x2, wave-tile 32x64.
// A: global->reg prefetch depth 4 -> cvt -> XOR-swizzled LDS (double buffer).
// B: direct global->MFMA-frag loads, depth-2 register pipeline, no LDS.
template <int S>
__global__ __launch_bounds__(512, 4) void k_gemm1(const float* __restrict__ A,
                                                  const bf16_t* __restrict__ Bt,
                                                  float* __restrict__ P) {
  constexpr int K = N_NODES;
  constexpr int KC = K / S;
  constexpr int NIT = KC / 32;  // 64 for S=4; multiple of 4
  __shared__ bf16_t As[2][128 * 32];  // 16 KB total, XOR-swizzled granules

  const int b = blockIdx.x;
  const int xcd = b & 7;
  const int i6 = b >> 3;
  const int n_tile = i6 & 3;
  const int s = (i6 >> 2) & (S - 1);
  const int mg = (i6 >> 2) / S;
  const int m0 = (mg * 8 + xcd) * 128;
  const int n0 = n_tile * 128;

  const int t = threadIdx.x;
  const int lane = t & 63;
  const int w = t >> 6;
  const int wr = w >> 1;  // 0..3: wave row (32 M-rows)
  const int wc = w & 1;   // 0..1: wave col (64 N-cols)
  const int lrow = lane & 15;
  const int quad = lane >> 4;
  const int pg = quad ^ (lrow & 3);  // XOR-swizzled granule for frag reads

  // A staging coords: 128 rows x 4 granules(8 f32 -> 8 bf16)
  const int sr = t >> 2;
  const int sq = t & 3;
  const int wofs = sr * 32 + ((sq ^ (sr & 3)) * 8);

  const float* ap = A + (size_t)(m0 + sr) * K + s * KC + sq * 8;
  const bf16_t* bp = Bt + (size_t)s * KC + quad * 8;  // + row*K + k0 later
  const int brow0 = n0 + wc * 64 + lrow;

  f32x4 pa0[4], pa1[4];   // A prefetch, depth 4
  bf16x8 bs[2][4];        // B frags, depth 2

  auto loadA = [&](int k0, int sl) {
    pa0[sl] = *(const f32x4*)(ap + k0);
    pa1[sl] = *(const f32x4*)(ap + k0 + 4);
  };
  auto loadB = [&](int k0, int sl) {
#pragma unroll
    for (int jj = 0; jj < 4; ++jj)
      bs[sl][jj] = *(const bf16x8*)(bp + (size_t)(brow0 + jj * 16) * K + k0);
  };
  auto stageA = [&](int sl, int buf) {
    bf16x8 av;
#pragma unroll
    for (int z = 0; z < 4; ++z) {
      av[z] = (bf16_t)pa0[sl][z];
      av[z + 4] = (bf16_t)pa1[sl][z];
    }
    *(bf16x8*)&As[buf][wofs] = av;
  };

  loadA(0, 0);
  loadA(32, 1);
  loadA(64, 2);
  loadA(96, 3);
  loadB(0, 0);
  loadB(32, 1);
  stageA(0, 0);
  f32x4 acc[2][4] = {};
  __syncthreads();

  int cur = 0;
  auto body = [&](int it, int sa, int sb, int snext) {
    if (it + 4 < NIT) loadA((it + 4) * 32, sa);
    const int rbase = wr * 32 + lrow;
    bf16x8 af0 = *(const bf16x8*)&As[cur][(rbase + 0) * 32 + pg * 8];
    bf16x8 af1 = *(const bf16x8*)&As[cur][(rbase + 16) * 32 + pg * 8];
#pragma unroll
    for (int jj = 0; jj < 4; ++jj) {
      acc[0][jj] = __builtin_amdgcn_mfma_f32_16x16x32_bf16(af0, bs[sb][jj], acc[0][jj], 0, 0, 0);
      acc[1][jj] = __builtin_amdgcn_mfma_f32_16x16x32_bf16(af1, bs[sb][jj], acc[1][jj], 0, 0, 0);
    }
    if (it + 2 < NIT) loadB((it + 2) * 32, sb);  // after MFMAs consume slot sb
    if (it + 1 < NIT) stageA(snext, cur ^ 1);
    __syncthreads();
    cur ^= 1;
  };

  for (int it4 = 0; it4 < NIT; it4 += 4) {
    body(it4 + 0, 0, 0, 1);
    body(it4 + 1, 1, 1, 2);
    body(it4 + 2, 2, 0, 3);
    body(it4 + 3, 3, 1, 0);
  }

  float* Pp = P + (size_t)s * N_NODES * DIM;
#pragma unroll
  for (int ii = 0; ii < 2; ++ii)
#pragma unroll
    for (int jj = 0; jj < 4; ++jj) {
      const int col = n0 + wc * 64 + jj * 16 + lrow;
#pragma unroll
      for (int r = 0; r < 4; ++r) {
        const int row = m0 + wr * 32 + ii * 16 + quad * 4 + r;
        Pp[(size_t)row * DIM + col] = acc[ii][jj][r];
      }
    }
}

// ---- GEMM2: out = relu((sum_s P[s]) @ W^T + b), fp32 out --------------------
template <int S>
__global__ __launch_bounds__(256, 2) void k_gemm2(const float* __restrict__ P,
                                                  const bf16_t* __restrict__ Bw,
                                                  const float* __restrict__ bias,
                                                  float* __restrict__ out) {
  constexpr int K = DIM;
  constexpr int LDA = 72;
  constexpr int LDB = 72;
  constexpr size_t PS = (size_t)N_NODES * DIM;
  __shared__ bf16_t As[64 * LDA];
  __shared__ bf16_t Bs[128 * LDB];

  const int b = blockIdx.x;
  const int n0 = (b & 3) * 128;
  const int m0 = (b >> 2) * 64;
  const int t = threadIdx.x;
  const int lane = t & 63;
  const int w = t >> 6;
  const int wr = w & 1;
  const int wc = w >> 1;
  const int lrow = lane & 15;
  const int quad = lane >> 4;
  const int ar = t >> 2, aq = t & 3;
  const int br = t >> 1, bq = t & 1;

  const float* ap = P + (size_t)(m0 + ar) * K + aq * 16;
  const bf16_t* bp = Bw + (size_t)(n0 + br) * K + bq * 32;
  bf16_t* aw = &As[ar * LDA + aq * 16];
  bf16_t* bw = &Bs[br * LDB + bq * 32];

  f32x4 acc[2][4] = {};

  for (int k0 = 0; k0 < K; k0 += 64) {
    f32x4 av[4];
#pragma unroll
    for (int z = 0; z < 4; ++z) av[z] = *(const f32x4*)(ap + k0 + z * 4);
#pragma unroll
    for (int s2 = 1; s2 < S; ++s2)
#pragma unroll
      for (int z = 0; z < 4; ++z) av[z] += *(const f32x4*)(ap + s2 * PS + k0 + z * 4);
    bf16x8 b0 = *(const bf16x8*)(bp + k0);
    bf16x8 b1 = *(const bf16x8*)(bp + k0 + 8);
    bf16x8 b2 = *(const bf16x8*)(bp + k0 + 16);
    bf16x8 b3 = *(const bf16x8*)(bp + k0 + 24);
    bf16x8 a0, a1;
#pragma unroll
    for (int z = 0; z < 4; ++z) {
      a0[z] = (bf16_t)av[0][z];
      a0[z + 4] = (bf16_t)av[1][z];
      a1[z] = (bf16_t)av[2][z];
      a1[z + 4] = (bf16_t)av[3][z];
    }
    __syncthreads();
    *(bf16x8*)aw = a0;
    *(bf16x8*)(aw + 8) = a1;
    *(bf16x8*)bw = b0;
    *(bf16x8*)(bw + 8) = b1;
    *(bf16x8*)(bw + 16) = b2;
    *(bf16x8*)(bw + 24) = b3;
    __syncthreads();
#pragma unroll
    for (int kk = 0; kk < 64; kk += 32) {
      bf16x8 af0 = *(const bf16x8*)&As[(wr * 32 + 0 + lrow) * LDA + kk + quad * 8];
      bf16x8 af1 = *(const bf16x8*)&As[(wr * 32 + 16 + lrow) * LDA + kk + quad * 8];
      bf16x8 bf0 = *(const bf16x8*)&Bs[(wc * 64 + 0 + lrow) * LDB + kk + quad * 8];
      bf16x8 bf1 = *(const bf16x8*)&Bs[(wc * 64 + 16 + lrow) * LDB + kk + quad * 8];
      bf16x8 bf2 = *(const bf16x8*)&Bs[(wc * 64 + 32 + lrow) * LDB + kk + quad * 8];
      bf16x8 bf3 = *(const bf16x8*)&Bs[(wc * 64 + 48 + lrow) * LDB + kk + quad * 8];
      acc[0][0] = __builtin_amdgcn_mfma_f32_16x16x32_bf16(af0, bf0, acc[0][0], 0, 0, 0);
      acc[0][1] = __builtin_amdgcn_mfma_f32_16x16x32_bf16(af0, bf1, acc[0][1], 0, 0, 0);
      acc[0][2] = __builtin_amdgcn_mfma_f32_16x16x32_bf16(af0, bf2, acc[0][2], 0, 0, 0);
      acc[0][3] = __builtin_amdgcn_mfma_f32_16x16x32_bf16(af0, bf3, acc[0][3], 0, 0, 0);
      acc[1][0] = __builtin_amdgcn_mfma_f32_16x16x32_bf16(af1, bf0, acc[1][0], 0, 0, 0);
      acc[1][1] = __builtin_amdgcn_mfma_f32_16x16x32_bf16(af1, bf1, acc[1][1], 0, 0, 0);
      acc[1][2] = __builtin_amdgcn_mfma_f32_16x16x32_bf16(af1, bf2, acc[1][2], 0, 0, 0);
      acc[1][3] = __builtin_amdgcn_mfma_f32_16x16x32_bf16(af1, bf3, acc[1][3], 0, 0, 0);
    }
  }

#pragma unroll
  for (int i = 0; i < 2; ++i)
#pragma unroll
    for (int j = 0; j < 4; ++j) {
      const int col = n0 + wc * 64 + j * 16 + lrow;
      const float bj = bias[col];
#pragma unroll
      for (int r = 0; r < 4; ++r) {
        const int row = m0 + wr * 32 + i * 16 + quad * 4 + r;
        float v = acc[i][j][r] + bj;
        out[(size_t)row * DIM + col] = v > 0.0f ? v : 0.0f;
      }
    }
}

extern "C" void kernel_launch(void* const* d_in, const int* in_sizes, int n_in,
                              void* d_out, int out_size, void* d_ws, size_t ws_size,
                              hipStream_t stream) {
  const float* x = (const float*)d_in[0];
  const float* adj = (const float*)d_in[1];
  const float* W = (const float*)d_in[2];
  const float* b = (const float*)d_in[3];
  float* out = (float*)d_out;

  bf16_t* xT = (bf16_t*)d_ws;
  bf16_t* Wb = xT + (size_t)DIM * N_NODES;
  float* P = (float*)(Wb + (size_t)DIM * DIM);
  const size_t base = (size_t)DIM * N_NODES * 2 + (size_t)DIM * DIM * 2;
  const size_t pslab = (size_t)N_NODES * DIM * 4;

  k_transpose_x<<<dim3(N_NODES / 64, DIM / 64), 256, 0, stream>>>(x, xT);
  k_cvt_w<<<dim3((DIM * DIM / 4) / 256), 256, 0, stream>>>(W, Wb);

  if (ws_size >= base + 4 * pslab) {
    k_gemm1<4><<<dim3(256 * 4), 512, 0, stream>>>(adj, xT, P);
    k_gemm2<4><<<dim3(512), 256, 0, stream>>>(P, Wb, b, out);
  } else {
    k_gemm1<1><<<dim3(256), 512, 0, stream>>>(adj, xT, P);
    k_gemm2<1><<<dim3(512), 256, 0, stream>>>(P, Wb, b, out);
  }
}